// Round 2
// baseline (834.828 us; speedup 1.0000x reference)
//
#include <hip/hip_runtime.h>
#include <stdint.h>
#include <stddef.h>

// ---------------------------------------------------------------------------
// LongRangeDW v2: x(8,128,128,128) -> nnstack(5C) -> 3 depthwise -> pointwise
// 5C->C -> +x.
// dw_kernel: 2 channels x 32-row band per block (37KB LDS -> 4 blocks/CU),
//   conflict-free LOAD_RB lane mapping, shfl-paired coalesced dwordx4 stores.
// y layout: [bl][k2 = k/2][p' = p ^ (((k2>>2)&3)<<3)] as dwords (lo=ce0,hi=ce1)
//   -- the p-swizzle makes gemm B-fragment LDS reads 2-way (free).
// gemm_kernel: w4 pre-swizzled ch-major (conflict-free A-frags), ping-pong
//   double-buffered staging (one barrier per kt, loads land during compute).
// ---------------------------------------------------------------------------

static constexpr int Cc  = 128;
static constexpr int C5  = 640;
static constexpr int LC2 = 160;            // LDS cols (128 + 16 guard each side)
static constexpr int NR2 = 58;             // 32 band + 13 halo each side
static constexpr int PS2 = NR2 * LC2 + 8;  // 9288 shorts; dword stride % 32 == 4

typedef __attribute__((ext_vector_type(8))) short short8;
typedef __attribute__((ext_vector_type(4))) float f32x4;

__device__ __forceinline__ uint16_t f2bf(float f) {
  uint32_t b = __float_as_uint(f);
  b += 0x7fffu + ((b >> 16) & 1u);      // RNE
  return (uint16_t)(b >> 16);
}
__device__ __forceinline__ float bflo(uint32_t v) { return __uint_as_float(v << 16); }
__device__ __forceinline__ float bfhi(uint32_t v) { return __uint_as_float(v & 0xffff0000u); }

__device__ __forceinline__ void async16(uint16_t* lds, const uint16_t* gm) {
  __builtin_amdgcn_global_load_lds(
      (const __attribute__((address_space(1))) uint32_t*)gm,
      (__attribute__((address_space(3))) uint32_t*)lds, 16, 0, 0);
}
__device__ __forceinline__ void async16w(uint32_t* lds, const uint32_t* gm) {
  __builtin_amdgcn_global_load_lds(
      (const __attribute__((address_space(1))) uint32_t*)gm,
      (__attribute__((address_space(3))) uint32_t*)lds, 16, 0, 0);
}

// ---------------------------------------------------------------------------
// prep: w4 -> bf16 swizzled [kt][ch][o][8] (ch-major per 64-k tile);
// combined dw weights cw2 (center folds w1+w3c), cw3; bias sums.
// ---------------------------------------------------------------------------
__global__ void prep_kernel(const float* __restrict__ w1, const float* __restrict__ b1,
                            const float* __restrict__ w2, const float* __restrict__ b2,
                            const float* __restrict__ w3, const float* __restrict__ b3,
                            const float* __restrict__ w4,
                            uint16_t* __restrict__ w4s, float* __restrict__ cw2,
                            float* __restrict__ cw3, float* __restrict__ bsum) {
  int i = blockIdx.x * 256 + threadIdx.x;
  if (i < Cc * C5) {
    int e  = i & 7;
    int o  = (i >> 3) & 127;
    int ch = (i >> 10) & 7;
    int kt = i >> 13;
    int k  = kt * 64 + ch * 8 + e;
    w4s[i] = f2bf(w4[o * 640 + k]);
  }
  if (i < C5) {
    bsum[i] = b1[i] + b2[i] + b3[i];
#pragma unroll
    for (int t = 0; t < 9; ++t) {
      float a = w2[i * 9 + t];
      if (t == 4) a += w1[i] + w3[i * 9 + 4];
      cw2[i * 9 + t] = a;
      cw3[i * 9 + t] = w3[i * 9 + t];
    }
  }
}

// ---------------------------------------------------------------------------
// dw_kernel: block = (band of 32 rows, channel-pair g, batch).
// lanes: ce=tid&1, jt=(tid>>1)&7 (16-col strip), ir=tid>>4 (rows ir, ir+16).
// m order: m0=below(+1,0) m1=above(-1,0) m2=right(0,+1) m3=left(0,-1) m4=center
// ---------------------------------------------------------------------------
__global__ __launch_bounds__(256, 4) void dw_kernel(
    const float* __restrict__ x, const float* __restrict__ cw2,
    const float* __restrict__ cw3, const float* __restrict__ bsum,
    uint32_t* __restrict__ yw, int b0) {
  __shared__ uint16_t xs[2 * PS2];    // 37152 B

  const int band = blockIdx.x;        // 0..3
  const int g    = blockIdx.y;        // 0..63 (channel pair)
  const int bl   = blockIdx.z;
  const int bb   = b0 + bl;
  const int i0   = band * 32;
  const int tid  = threadIdx.x;

  // ---- stage x (2 channels, rows i0-13 .. i0+44) into LDS bf16, zero guards
#pragma unroll
  for (int it = 0; it < 19; ++it) {
    int idx = it * 256 + tid;
    if (idx < 4640) {
      int cel  = idx / 2320;
      int rem  = idx - cel * 2320;
      int rr   = rem / 40;
      int col4 = rem - rr * 40;
      int gi = i0 - 13 + rr;
      int gj = col4 * 4 - 16;
      float4 v = make_float4(0.f, 0.f, 0.f, 0.f);
      if ((unsigned)gi < 128u && col4 >= 4 && col4 < 36) {
        v = *(const float4*)(x + (((size_t)(bb * Cc + 2 * g + cel)) << 14) + (gi << 7) + gj);
      }
      ushort4 h;
      h.x = f2bf(v.x); h.y = f2bf(v.y); h.z = f2bf(v.z); h.w = f2bf(v.w);
      *(ushort4*)(xs + cel * PS2 + rr * LC2 + col4 * 4) = h;
    }
  }
  __syncthreads();

  const int ce = tid & 1;
  const int jt = (tid >> 1) & 7;
  const int ir = tid >> 4;            // 0..15
  const int j0 = jt * 16;
  const int c  = 2 * g + ce;
  const int swz = ((g >> 2) & 3) << 3;   // y p-swizzle bits (block-uniform)

  float rb[48];   // rb[16+t] <-> global col j0+t
#define LOAD_RB(ROW)                                                      \
  do {                                                                    \
    const uint16_t* _p = xs + ce * PS2 + (ROW) * LC2 + j0;                \
    _Pragma("unroll") for (int _u = 0; _u < 6; ++_u) {                    \
      uint4 _q = *(const uint4*)(_p + _u * 8);                            \
      rb[_u * 8 + 0] = bflo(_q.x); rb[_u * 8 + 1] = bfhi(_q.x);           \
      rb[_u * 8 + 2] = bflo(_q.y); rb[_u * 8 + 3] = bfhi(_q.y);           \
      rb[_u * 8 + 4] = bflo(_q.z); rb[_u * 8 + 5] = bfhi(_q.z);           \
      rb[_u * 8 + 6] = bflo(_q.w); rb[_u * 8 + 7] = bfhi(_q.w);           \
    }                                                                     \
  } while (0)

  // pack 16 bf16 outputs, pair-interleave ce0/ce1 via shfl_xor(1), store 32B
#define STORE16(ACC, MVAL)                                                \
  do {                                                                    \
    uint32_t d0[8];                                                       \
    _Pragma("unroll") for (int _k = 0; _k < 8; ++_k)                      \
      d0[_k] = (uint32_t)f2bf(ACC[2 * _k]) |                              \
               ((uint32_t)f2bf(ACC[2 * _k + 1]) << 16);                   \
    uint32_t t0[4];                                                       \
    _Pragma("unroll") for (int _k = 0; _k < 4; ++_k)                      \
      t0[_k] = (uint32_t)__shfl_xor((int)(ce ? d0[_k] : d0[4 + _k]), 1, 64); \
    uint32_t F[8];                                                        \
    _Pragma("unroll") for (int _u = 0; _u < 4; ++_u) {                    \
      uint32_t _a = ce ? t0[_u] : d0[_u];                                 \
      uint32_t _b = ce ? d0[4 + _u] : t0[_u];                             \
      F[2 * _u]     = (_a & 0xffffu) | (_b << 16);                        \
      F[2 * _u + 1] = (_a >> 16) | (_b & 0xffff0000u);                    \
    }                                                                     \
    uint32_t* _dst = yw + (((size_t)(bl * 320 + (MVAL) * 64 + g)) << 14)  \
                     + ((size_t)i << 7) + ((j0 + ce * 8) ^ swz);          \
    *(uint4*)(_dst)     = make_uint4(F[0], F[1], F[2], F[3]);             \
    *(uint4*)(_dst + 4) = make_uint4(F[4], F[5], F[6], F[7]);             \
  } while (0)

  // =======================================================================
  // Group A: m4 (center, aj=0), m2 (right, aj=+1), m3 (left, aj=-1).
  // =======================================================================
  {
    float w2r[3][9], w3r[3][9], bs[3];
    const int msA[3] = {4, 2, 3};
#pragma unroll
    for (int mi = 0; mi < 3; ++mi) {
      int k = msA[mi] * Cc + c;
#pragma unroll
      for (int t = 0; t < 9; ++t) {
        w2r[mi][t] = cw2[k * 9 + t];
        w3r[mi][t] = cw3[k * 9 + t];
      }
      bs[mi] = bsum[k];
    }

#pragma unroll
    for (int it2 = 0; it2 < 2; ++it2) {
      const int i     = i0 + ir + 16 * it2;
      const int rbase = ir + 16 * it2 + 13;
      float acc[3][16];
#pragma unroll
      for (int mi = 0; mi < 3; ++mi)
#pragma unroll
        for (int jj = 0; jj < 16; ++jj) acc[mi][jj] = bs[mi];

#define AROW3(DLT, WARR, UB, DD)                                          \
      do {                                                                \
        LOAD_RB(rbase + (DLT));                                           \
        _Pragma("unroll") for (int mi = 0; mi < 3; ++mi) {                \
          const int aj = (mi == 0) ? 0 : ((mi == 1) ? 1 : -1);            \
          _Pragma("unroll") for (int v = 0; v < 3; ++v) {                 \
            const float w = WARR[mi][(UB) + v];                           \
            const int e = 16 + (DD) * (v - 1) + aj;                       \
            _Pragma("unroll") for (int jj = 0; jj < 16; ++jj)             \
              acc[mi][jj] += w * rb[e + jj];                              \
          }                                                               \
        }                                                                 \
      } while (0)

      AROW3(-12, w3r, 0, 12);
      if (j0 == 0)   acc[1][11] -= w3r[1][0] * rb[16];
      if (j0 == 112) acc[2][4]  -= w3r[2][2] * rb[31];

      AROW3(-8, w2r, 0, 8);
      if (j0 == 0)   acc[1][7]  -= w2r[1][0] * rb[16];
      if (j0 == 112) acc[2][8]  -= w2r[2][2] * rb[31];

      {  // center row: w2 u=1 (3 taps) + w3[3](-12) + w3[5](+12)
        LOAD_RB(rbase);
#pragma unroll
        for (int mi = 0; mi < 3; ++mi) {
          const int aj = (mi == 0) ? 0 : ((mi == 1) ? 1 : -1);
#pragma unroll
          for (int v = 0; v < 3; ++v) {
            const float w = w2r[mi][3 + v];
            const int e = 16 + 8 * (v - 1) + aj;
#pragma unroll
            for (int jj = 0; jj < 16; ++jj) acc[mi][jj] += w * rb[e + jj];
          }
          {
            const float w = w3r[mi][3]; const int e = 4 + aj;
#pragma unroll
            for (int jj = 0; jj < 16; ++jj) acc[mi][jj] += w * rb[e + jj];
          }
          {
            const float w = w3r[mi][5]; const int e = 28 + aj;
#pragma unroll
            for (int jj = 0; jj < 16; ++jj) acc[mi][jj] += w * rb[e + jj];
          }
        }
        if (j0 == 0)   { acc[1][7] -= w2r[1][3] * rb[16]; acc[1][11] -= w3r[1][3] * rb[16]; }
        if (j0 == 112) { acc[2][8] -= w2r[2][5] * rb[31]; acc[2][4]  -= w3r[2][5] * rb[31]; }
      }

      AROW3(8, w2r, 6, 8);
      if (j0 == 0)   acc[1][7]  -= w2r[1][6] * rb[16];
      if (j0 == 112) acc[2][8]  -= w2r[2][8] * rb[31];

      AROW3(12, w3r, 6, 12);
      if (j0 == 0)   acc[1][11] -= w3r[1][6] * rb[16];
      if (j0 == 112) acc[2][4]  -= w3r[2][8] * rb[31];
#undef AROW3

      STORE16(acc[0], 4);
      STORE16(acc[1], 2);
      STORE16(acc[2], 3);
    }
  }

  // =======================================================================
  // Group B: m0 (below, ai=+1, mask x-row 0), m1 (above, ai=-1, mask 127).
  // =======================================================================
  {
    float w2r[2][9], w3r[2][9], bs[2];
#pragma unroll
    for (int mi = 0; mi < 2; ++mi) {
      int k = mi * Cc + c;
#pragma unroll
      for (int t = 0; t < 9; ++t) {
        w2r[mi][t] = cw2[k * 9 + t];
        w3r[mi][t] = cw3[k * 9 + t];
      }
      bs[mi] = bsum[k];
    }

#pragma unroll
    for (int it2 = 0; it2 < 2; ++it2) {
      const int i     = i0 + ir + 16 * it2;
      const int rbase = ir + 16 * it2 + 13;
      float acc[2][16];
#pragma unroll
      for (int mi = 0; mi < 2; ++mi)
#pragma unroll
        for (int jj = 0; jj < 16; ++jj) acc[mi][jj] = bs[mi];

#define BROW3(MI, DLT, WARR, UB, DD, BADROW)                              \
      do {                                                                \
        LOAD_RB(rbase + (DLT));                                           \
        const float sel = ((i + (DLT)) == (BADROW)) ? 0.f : 1.f;          \
        _Pragma("unroll") for (int v = 0; v < 3; ++v) {                   \
          const float w = WARR[MI][(UB) + v] * sel;                       \
          const int e = 16 + (DD) * (v - 1);                              \
          _Pragma("unroll") for (int jj = 0; jj < 16; ++jj)               \
            acc[MI][jj] += w * rb[e + jj];                                \
        }                                                                 \
      } while (0)

#define BROWC(MI, DLT, BADROW)                                            \
      do {                                                                \
        LOAD_RB(rbase + (DLT));                                           \
        const float sel = ((i + (DLT)) == (BADROW)) ? 0.f : 1.f;          \
        _Pragma("unroll") for (int v = 0; v < 3; ++v) {                   \
          const float w = w2r[MI][3 + v] * sel;                           \
          const int e = 16 + 8 * (v - 1);                                 \
          _Pragma("unroll") for (int jj = 0; jj < 16; ++jj)               \
            acc[MI][jj] += w * rb[e + jj];                                \
        }                                                                 \
        {                                                                 \
          const float w = w3r[MI][3] * sel;                               \
          _Pragma("unroll") for (int jj = 0; jj < 16; ++jj)               \
            acc[MI][jj] += w * rb[4 + jj];                                \
        }                                                                 \
        {                                                                 \
          const float w = w3r[MI][5] * sel;                               \
          _Pragma("unroll") for (int jj = 0; jj < 16; ++jj)               \
            acc[MI][jj] += w * rb[28 + jj];                               \
        }                                                                 \
      } while (0)

      // m0: deltas {-11,-7,1,9,13}
      BROW3(0, -11, w3r, 0, 12, 0);
      BROW3(0, -7,  w2r, 0, 8, 0);
      BROWC(0, 1, 0);
      BROW3(0, 9,   w2r, 6, 8, 0);
      BROW3(0, 13,  w3r, 6, 12, 0);
      // m1: deltas {-13,-9,-1,7,11}
      BROW3(1, -13, w3r, 0, 12, 127);
      BROW3(1, -9,  w2r, 0, 8, 127);
      BROWC(1, -1, 127);
      BROW3(1, 7,   w2r, 6, 8, 127);
      BROW3(1, 11,  w3r, 6, 12, 127);
#undef BROW3
#undef BROWC

      STORE16(acc[0], 0);
      STORE16(acc[1], 1);
    }
  }
#undef LOAD_RB
#undef STORE16
}

// ---------------------------------------------------------------------------
// gemm_kernel: out[b,o,p] = sum_k w4[o,k]*y[b,k,p] + b4[o] + x[b,o,p]
// A = w4s (ch-major swizzle), B = y [k2][p'] dwords. Ping-pong double buffer.
// ---------------------------------------------------------------------------
__global__ __launch_bounds__(256, 2) void gemm_kernel(
    const uint16_t* __restrict__ w4s, const uint32_t* __restrict__ y,
    const float* __restrict__ x, const float* __restrict__ b4,
    float* __restrict__ out, int b0) {
  __shared__ uint16_t As[2][128 * 64];   // [ch][o][8] image, 16 KiB each
  __shared__ uint32_t Bs[2][32 * 128];   // [k2l][p'] dwords, 16 KiB each

  const int tid  = threadIdx.x;
  const int lane = tid & 63;
  const int wave = tid >> 6;
  const int p0   = blockIdx.x * 128;
  const int bl   = blockIdx.y;
  const int bb   = b0 + bl;

  const int col = lane & 15;
  const int q   = lane >> 4;
  const int o_base = (wave >> 1) * 64;
  const int p_base = (wave & 1) * 64;

  f32x4 acc[4][4];
#pragma unroll
  for (int fm = 0; fm < 4; ++fm)
#pragma unroll
    for (int fn = 0; fn < 4; ++fn) acc[fm][fn] = (f32x4){0.f, 0.f, 0.f, 0.f};

  auto stage = [&](int kt, int bufi) {
#pragma unroll
    for (int l = 0; l < 4; ++l) {
      int u = (wave * 4 + l) * 64 + lane;
      async16(&As[bufi][u * 8], w4s + kt * 8192 + u * 8);
    }
#pragma unroll
    for (int l = 0; l < 4; ++l) {
      int u   = (wave * 4 + l) * 64 + lane;
      int k2l = u >> 5, pu = u & 31;
      async16w(&Bs[bufi][u * 4],
               y + (((size_t)(bl * 320 + kt * 32 + k2l)) << 14) + p0 + pu * 4);
    }
  };

  stage(0, 0);
  for (int kt = 0; kt < 10; ++kt) {
    __syncthreads();                 // drains stage(kt); loads had full compute phase
    if (kt < 9) stage(kt + 1, (kt + 1) & 1);
    const int bufi = kt & 1;
    const uint16_t* A = As[bufi];
    const uint32_t* B = Bs[bufi];
#pragma unroll
    for (int kk = 0; kk < 2; ++kk) {
      short8 af[4], bfr[4];
#pragma unroll
      for (int fm = 0; fm < 4; ++fm) {
        int o = o_base + fm * 16 + col;
        af[fm] = *(const short8*)(A + (((kk * 4 + q) * 128) + o) * 8);
      }
#pragma unroll
      for (int fn = 0; fn < 4; ++fn) {
        int pl  = p_base + fn * 16 + col;
        int pls = pl ^ (q << 3);
        union { short8 s; uint32_t u[4]; } bu;
#pragma unroll
        for (int i2 = 0; i2 < 4; ++i2)
          bu.u[i2] = B[(kk * 16 + q * 4 + i2) * 128 + pls];
        bfr[fn] = bu.s;
      }
#pragma unroll
      for (int fm = 0; fm < 4; ++fm)
#pragma unroll
        for (int fn = 0; fn < 4; ++fn)
          acc[fm][fn] = __builtin_amdgcn_mfma_f32_16x16x32_bf16(af[fm], bfr[fn], acc[fm][fn], 0, 0, 0);
    }
  }

  // epilogue: + b4 + residual x ; C/D layout col=lane&15, row=q*4+r
#pragma unroll
  for (int fm = 0; fm < 4; ++fm) {
#pragma unroll
    for (int fn = 0; fn < 4; ++fn) {
      int pg = p0 + p_base + fn * 16 + col;
#pragma unroll
      for (int r = 0; r < 4; ++r) {
        int oo = o_base + fm * 16 + q * 4 + r;
        size_t oi = ((size_t)(bb * 128 + oo) << 14) + pg;
        out[oi] = acc[fm][fn][r] + b4[oo] + x[oi];
      }
    }
  }
}

// ---------------------------------------------------------------------------
extern "C" void kernel_launch(void* const* d_in, const int* in_sizes, int n_in,
                              void* d_out, int out_size, void* d_ws, size_t ws_size,
                              hipStream_t stream) {
  const float* x  = (const float*)d_in[0];
  const float* w1 = (const float*)d_in[1];
  const float* b1 = (const float*)d_in[2];
  const float* w2 = (const float*)d_in[3];
  const float* b2 = (const float*)d_in[4];
  const float* w3 = (const float*)d_in[5];
  const float* b3 = (const float*)d_in[6];
  const float* w4 = (const float*)d_in[7];
  const float* b4 = (const float*)d_in[8];
  float* out = (float*)d_out;

  char* ws = (char*)d_ws;
  uint16_t* w4s  = (uint16_t*)ws;              // 163840 B
  float*    cw2  = (float*)(ws + 163840);      // 23040 B
  float*    cw3  = (float*)(ws + 186880);      // 23040 B
  float*    bsum = (float*)(ws + 209920);      // 2560 B
  uint32_t* y    = (uint32_t*)(ws + (1 << 20));

  const size_t per_b = (size_t)320 * 16384 * 4;  // 20 MiB per batch
  int nbc = 4;                                    // y chunk ~80 MiB -> L3
  while (nbc > 1 && (size_t)(1 << 20) + (size_t)nbc * per_b > ws_size) nbc >>= 1;

  hipLaunchKernelGGL(prep_kernel, dim3(320), dim3(256), 0, stream,
                     w1, b1, w2, b2, w3, b3, w4, w4s, cw2, cw3, bsum);
  for (int b0 = 0; b0 < 8; b0 += nbc) {
    int nb = (8 - b0) < nbc ? (8 - b0) : nbc;
    hipLaunchKernelGGL(dw_kernel, dim3(4, 64, nb), dim3(256), 0, stream,
                       x, cw2, cw3, bsum, y, b0);
    hipLaunchKernelGGL(gemm_kernel, dim3(128, nb), dim3(256), 0, stream,
                       w4s, y, x, b4, out, b0);
  }
}

// Round 3
// 662.527 us; speedup vs baseline: 1.2601x; 1.2601x over previous
//
#include <hip/hip_runtime.h>
#include <stdint.h>
#include <stddef.h>

// ---------------------------------------------------------------------------
// LongRangeDW v3: fix R2's spill disaster. dw_kernel processes one m-shift at
// a time (live regs ~110 < 128 cap) so __launch_bounds__(256,4) holds without
// scratch spills. Stores/staging/y-layout identical to v2 (validated).
// gemm_kernel unchanged from v2.
// ---------------------------------------------------------------------------

static constexpr int Cc  = 128;
static constexpr int C5  = 640;
static constexpr int LC2 = 160;            // LDS cols (128 + 16 guard each side)
static constexpr int NR2 = 58;             // 32 band + 13 halo each side
static constexpr int PS2 = NR2 * LC2 + 8;  // 9288 shorts

typedef __attribute__((ext_vector_type(8))) short short8;
typedef __attribute__((ext_vector_type(4))) float f32x4;

__device__ __forceinline__ uint16_t f2bf(float f) {
  uint32_t b = __float_as_uint(f);
  b += 0x7fffu + ((b >> 16) & 1u);      // RNE
  return (uint16_t)(b >> 16);
}
__device__ __forceinline__ float bflo(uint32_t v) { return __uint_as_float(v << 16); }
__device__ __forceinline__ float bfhi(uint32_t v) { return __uint_as_float(v & 0xffff0000u); }

__device__ __forceinline__ void async16(uint16_t* lds, const uint16_t* gm) {
  __builtin_amdgcn_global_load_lds(
      (const __attribute__((address_space(1))) uint32_t*)gm,
      (__attribute__((address_space(3))) uint32_t*)lds, 16, 0, 0);
}
__device__ __forceinline__ void async16w(uint32_t* lds, const uint32_t* gm) {
  __builtin_amdgcn_global_load_lds(
      (const __attribute__((address_space(1))) uint32_t*)gm,
      (__attribute__((address_space(3))) uint32_t*)lds, 16, 0, 0);
}

// ---------------------------------------------------------------------------
__global__ void prep_kernel(const float* __restrict__ w1, const float* __restrict__ b1,
                            const float* __restrict__ w2, const float* __restrict__ b2,
                            const float* __restrict__ w3, const float* __restrict__ b3,
                            const float* __restrict__ w4,
                            uint16_t* __restrict__ w4s, float* __restrict__ cw2,
                            float* __restrict__ cw3, float* __restrict__ bsum) {
  int i = blockIdx.x * 256 + threadIdx.x;
  if (i < Cc * C5) {
    int e  = i & 7;
    int o  = (i >> 3) & 127;
    int ch = (i >> 10) & 7;
    int kt = i >> 13;
    int k  = kt * 64 + ch * 8 + e;
    w4s[i] = f2bf(w4[o * 640 + k]);
  }
  if (i < C5) {
    bsum[i] = b1[i] + b2[i] + b3[i];
#pragma unroll
    for (int t = 0; t < 9; ++t) {
      float a = w2[i * 9 + t];
      if (t == 4) a += w1[i] + w3[i * 9 + 4];
      cw2[i * 9 + t] = a;
      cw3[i * 9 + t] = w3[i * 9 + t];
    }
  }
}

// ---------------------------------------------------------------------------
// dw_kernel: block = (32-row band, channel-pair g, batch). One m at a time.
// m order: m0=below(+1,0) m1=above(-1,0) m2=right(0,+1) m3=left(0,-1) m4=center
// y layout: [bl][k2=k/2][p ^ (((k2>>2)&3)<<3)] dwords (lo=ce0, hi=ce1).
// ---------------------------------------------------------------------------
__global__ __launch_bounds__(256, 4) void dw_kernel(
    const float* __restrict__ x, const float* __restrict__ cw2,
    const float* __restrict__ cw3, const float* __restrict__ bsum,
    uint32_t* __restrict__ yw, int b0) {
  __shared__ uint16_t xs[2 * PS2];    // 37152 B

  const int band = blockIdx.x;        // 0..3
  const int g    = blockIdx.y;        // 0..63 (channel pair)
  const int bl   = blockIdx.z;
  const int bb   = b0 + bl;
  const int i0   = band * 32;
  const int tid  = threadIdx.x;

  // ---- stage x (2 channels, rows i0-13 .. i0+44) into LDS bf16, zero guards
#pragma unroll
  for (int it = 0; it < 19; ++it) {
    int idx = it * 256 + tid;
    if (idx < 4640) {
      int cel  = idx / 2320;
      int rem  = idx - cel * 2320;
      int rr   = rem / 40;
      int col4 = rem - rr * 40;
      int gi = i0 - 13 + rr;
      int gj = col4 * 4 - 16;
      float4 v = make_float4(0.f, 0.f, 0.f, 0.f);
      if ((unsigned)gi < 128u && col4 >= 4 && col4 < 36) {
        v = *(const float4*)(x + (((size_t)(bb * Cc + 2 * g + cel)) << 14) + (gi << 7) + gj);
      }
      ushort4 h;
      h.x = f2bf(v.x); h.y = f2bf(v.y); h.z = f2bf(v.z); h.w = f2bf(v.w);
      *(ushort4*)(xs + cel * PS2 + rr * LC2 + col4 * 4) = h;
    }
  }
  __syncthreads();

  const int ce = tid & 1;
  const int jt = (tid >> 1) & 7;
  const int ir = tid >> 4;            // 0..15
  const int j0 = jt * 16;
  const int c  = 2 * g + ce;
  const int swz = ((g >> 2) & 3) << 3;

  float rb[48];   // rb[16+t] <-> global col j0+t
#define LOAD_RB(ROW)                                                      \
  do {                                                                    \
    const uint16_t* _p = xs + ce * PS2 + (ROW) * LC2 + j0;                \
    _Pragma("unroll") for (int _u = 0; _u < 6; ++_u) {                    \
      uint4 _q = *(const uint4*)(_p + _u * 8);                            \
      rb[_u * 8 + 0] = bflo(_q.x); rb[_u * 8 + 1] = bfhi(_q.x);           \
      rb[_u * 8 + 2] = bflo(_q.y); rb[_u * 8 + 3] = bfhi(_q.y);           \
      rb[_u * 8 + 4] = bflo(_q.z); rb[_u * 8 + 5] = bfhi(_q.z);           \
      rb[_u * 8 + 6] = bflo(_q.w); rb[_u * 8 + 7] = bfhi(_q.w);           \
    }                                                                     \
  } while (0)

#define STORE16(ACC, MVAL)                                                \
  do {                                                                    \
    uint32_t d0[8];                                                       \
    _Pragma("unroll") for (int _k = 0; _k < 8; ++_k)                      \
      d0[_k] = (uint32_t)f2bf(ACC[2 * _k]) |                              \
               ((uint32_t)f2bf(ACC[2 * _k + 1]) << 16);                   \
    uint32_t t0[4];                                                       \
    _Pragma("unroll") for (int _k = 0; _k < 4; ++_k)                      \
      t0[_k] = (uint32_t)__shfl_xor((int)(ce ? d0[_k] : d0[4 + _k]), 1, 64); \
    uint32_t F[8];                                                        \
    _Pragma("unroll") for (int _u = 0; _u < 4; ++_u) {                    \
      uint32_t _a = ce ? t0[_u] : d0[_u];                                 \
      uint32_t _b = ce ? d0[4 + _u] : t0[_u];                             \
      F[2 * _u]     = (_a & 0xffffu) | (_b << 16);                        \
      F[2 * _u + 1] = (_a >> 16) | (_b & 0xffff0000u);                    \
    }                                                                     \
    uint32_t* _dst = yw + (((size_t)(bl * 320 + (MVAL) * 64 + g)) << 14)  \
                     + ((size_t)i << 7) + ((j0 + ce * 8) ^ swz);          \
    *(uint4*)(_dst)     = make_uint4(F[0], F[1], F[2], F[3]);             \
    *(uint4*)(_dst + 4) = make_uint4(F[4], F[5], F[6], F[7]);             \
  } while (0)

  // standard 3-tap row: LOAD_RB(rbase+DLT), taps WARR[UB..UB+2] at col
  // stride DD, col shift AJ; row-masked when BAD>=0 and x-row == BAD.
#define ROWSTD(DLT, WARR, UB, DD, AJ, BAD)                                \
  do {                                                                    \
    LOAD_RB(rbase + (DLT));                                               \
    const float sel = ((BAD) >= 0 && (i + (DLT)) == (BAD)) ? 0.f : 1.f;   \
    _Pragma("unroll") for (int v = 0; v < 3; ++v) {                       \
      const float w = WARR[(UB) + v] * sel;                               \
      const int e = 16 + (DD) * (v - 1) + (AJ);                           \
      _Pragma("unroll") for (int jj = 0; jj < 16; ++jj)                   \
        acc[jj] += w * rb[e + jj];                                        \
    }                                                                     \
  } while (0)

  // center row: w2[3..5] stride 8 + w3[3]@-12 + w3[5]@+12
#define ROWCTR(DLT, AJ, BAD)                                              \
  do {                                                                    \
    LOAD_RB(rbase + (DLT));                                               \
    const float sel = ((BAD) >= 0 && (i + (DLT)) == (BAD)) ? 0.f : 1.f;   \
    _Pragma("unroll") for (int v = 0; v < 3; ++v) {                       \
      const float w = w2r[3 + v] * sel;                                   \
      const int e = 16 + 8 * (v - 1) + (AJ);                              \
      _Pragma("unroll") for (int jj = 0; jj < 16; ++jj)                   \
        acc[jj] += w * rb[e + jj];                                        \
    }                                                                     \
    { const float w = w3r[3] * sel;                                       \
      _Pragma("unroll") for (int jj = 0; jj < 16; ++jj)                   \
        acc[jj] += w * rb[4 + (AJ) + jj]; }                               \
    { const float w = w3r[5] * sel;                                       \
      _Pragma("unroll") for (int jj = 0; jj < 16; ++jj)                   \
        acc[jj] += w * rb[28 + (AJ) + jj]; }                              \
  } while (0)

#define LOAD_W(M)                                                         \
  float w2r[9], w3r[9], bs;                                               \
  {                                                                       \
    int k = (M) * Cc + c;                                                 \
    _Pragma("unroll") for (int t = 0; t < 9; ++t) {                       \
      w2r[t] = cw2[k * 9 + t];                                            \
      w3r[t] = cw3[k * 9 + t];                                            \
    }                                                                     \
    bs = bsum[k];                                                         \
  }

#define INIT_ACC float acc[16]; _Pragma("unroll") \
  for (int jj = 0; jj < 16; ++jj) acc[jj] = bs;

  // ---- m0: below (ai=+1, aj=0), row deltas {-11,-7,1,9,13}, mask x-row 0
  {
    LOAD_W(0);
#pragma unroll
    for (int it2 = 0; it2 < 2; ++it2) {
      const int i = i0 + ir + 16 * it2;
      const int rbase = ir + 16 * it2 + 13;
      INIT_ACC;
      ROWSTD(-11, w3r, 0, 12, 0, 0);
      ROWSTD(-7,  w2r, 0, 8,  0, 0);
      ROWCTR(1, 0, 0);
      ROWSTD(9,   w2r, 6, 8,  0, 0);
      ROWSTD(13,  w3r, 6, 12, 0, 0);
      STORE16(acc, 0);
    }
  }
  // ---- m1: above (ai=-1, aj=0), deltas {-13,-9,-1,7,11}, mask x-row 127
  {
    LOAD_W(1);
#pragma unroll
    for (int it2 = 0; it2 < 2; ++it2) {
      const int i = i0 + ir + 16 * it2;
      const int rbase = ir + 16 * it2 + 13;
      INIT_ACC;
      ROWSTD(-13, w3r, 0, 12, 0, 127);
      ROWSTD(-9,  w2r, 0, 8,  0, 127);
      ROWCTR(-1, 0, 127);
      ROWSTD(7,   w2r, 6, 8,  0, 127);
      ROWSTD(11,  w3r, 6, 12, 0, 127);
      STORE16(acc, 1);
    }
  }
  // ---- m2: right (aj=+1), deltas {-12,-8,0,8,12}, left-edge fixes at j0==0
  {
    LOAD_W(2);
#pragma unroll
    for (int it2 = 0; it2 < 2; ++it2) {
      const int i = i0 + ir + 16 * it2;
      const int rbase = ir + 16 * it2 + 13;
      INIT_ACC;
      ROWSTD(-12, w3r, 0, 12, 1, -1);
      if (j0 == 0) acc[11] -= w3r[0] * rb[16];
      ROWSTD(-8,  w2r, 0, 8,  1, -1);
      if (j0 == 0) acc[7]  -= w2r[0] * rb[16];
      ROWCTR(0, 1, -1);
      if (j0 == 0) { acc[7] -= w2r[3] * rb[16]; acc[11] -= w3r[3] * rb[16]; }
      ROWSTD(8,   w2r, 6, 8,  1, -1);
      if (j0 == 0) acc[7]  -= w2r[6] * rb[16];
      ROWSTD(12,  w3r, 6, 12, 1, -1);
      if (j0 == 0) acc[11] -= w3r[6] * rb[16];
      STORE16(acc, 2);
    }
  }
  // ---- m3: left (aj=-1), right-edge fixes at j0==112
  {
    LOAD_W(3);
#pragma unroll
    for (int it2 = 0; it2 < 2; ++it2) {
      const int i = i0 + ir + 16 * it2;
      const int rbase = ir + 16 * it2 + 13;
      INIT_ACC;
      ROWSTD(-12, w3r, 0, 12, -1, -1);
      if (j0 == 112) acc[4] -= w3r[2] * rb[31];
      ROWSTD(-8,  w2r, 0, 8,  -1, -1);
      if (j0 == 112) acc[8] -= w2r[2] * rb[31];
      ROWCTR(0, -1, -1);
      if (j0 == 112) { acc[8] -= w2r[5] * rb[31]; acc[4] -= w3r[5] * rb[31]; }
      ROWSTD(8,   w2r, 6, 8,  -1, -1);
      if (j0 == 112) acc[8] -= w2r[8] * rb[31];
      ROWSTD(12,  w3r, 6, 12, -1, -1);
      if (j0 == 112) acc[4] -= w3r[8] * rb[31];
      STORE16(acc, 3);
    }
  }
  // ---- m4: center (aj=0)
  {
    LOAD_W(4);
#pragma unroll
    for (int it2 = 0; it2 < 2; ++it2) {
      const int i = i0 + ir + 16 * it2;
      const int rbase = ir + 16 * it2 + 13;
      INIT_ACC;
      ROWSTD(-12, w3r, 0, 12, 0, -1);
      ROWSTD(-8,  w2r, 0, 8,  0, -1);
      ROWCTR(0, 0, -1);
      ROWSTD(8,   w2r, 6, 8,  0, -1);
      ROWSTD(12,  w3r, 6, 12, 0, -1);
      STORE16(acc, 4);
    }
  }
#undef LOAD_RB
#undef STORE16
#undef ROWSTD
#undef ROWCTR
#undef LOAD_W
#undef INIT_ACC
}

// ---------------------------------------------------------------------------
// gemm_kernel: out[b,o,p] = sum_k w4[o,k]*y[b,k,p] + b4[o] + x[b,o,p]
// (unchanged from v2)
// ---------------------------------------------------------------------------
__global__ __launch_bounds__(256, 2) void gemm_kernel(
    const uint16_t* __restrict__ w4s, const uint32_t* __restrict__ y,
    const float* __restrict__ x, const float* __restrict__ b4,
    float* __restrict__ out, int b0) {
  __shared__ uint16_t As[2][128 * 64];
  __shared__ uint32_t Bs[2][32 * 128];

  const int tid  = threadIdx.x;
  const int lane = tid & 63;
  const int wave = tid >> 6;
  const int p0   = blockIdx.x * 128;
  const int bl   = blockIdx.y;
  const int bb   = b0 + bl;

  const int col = lane & 15;
  const int q   = lane >> 4;
  const int o_base = (wave >> 1) * 64;
  const int p_base = (wave & 1) * 64;

  f32x4 acc[4][4];
#pragma unroll
  for (int fm = 0; fm < 4; ++fm)
#pragma unroll
    for (int fn = 0; fn < 4; ++fn) acc[fm][fn] = (f32x4){0.f, 0.f, 0.f, 0.f};

  auto stage = [&](int kt, int bufi) {
#pragma unroll
    for (int l = 0; l < 4; ++l) {
      int u = (wave * 4 + l) * 64 + lane;
      async16(&As[bufi][u * 8], w4s + kt * 8192 + u * 8);
    }
#pragma unroll
    for (int l = 0; l < 4; ++l) {
      int u   = (wave * 4 + l) * 64 + lane;
      int k2l = u >> 5, pu = u & 31;
      async16w(&Bs[bufi][u * 4],
               y + (((size_t)(bl * 320 + kt * 32 + k2l)) << 14) + p0 + pu * 4);
    }
  };

  stage(0, 0);
  for (int kt = 0; kt < 10; ++kt) {
    __syncthreads();
    if (kt < 9) stage(kt + 1, (kt + 1) & 1);
    const int bufi = kt & 1;
    const uint16_t* A = As[bufi];
    const uint32_t* B = Bs[bufi];
#pragma unroll
    for (int kk = 0; kk < 2; ++kk) {
      short8 af[4], bfr[4];
#pragma unroll
      for (int fm = 0; fm < 4; ++fm) {
        int o = o_base + fm * 16 + col;
        af[fm] = *(const short8*)(A + (((kk * 4 + q) * 128) + o) * 8);
      }
#pragma unroll
      for (int fn = 0; fn < 4; ++fn) {
        int pl  = p_base + fn * 16 + col;
        int pls = pl ^ (q << 3);
        union { short8 s; uint32_t u[4]; } bu;
#pragma unroll
        for (int i2 = 0; i2 < 4; ++i2)
          bu.u[i2] = B[(kk * 16 + q * 4 + i2) * 128 + pls];
        bfr[fn] = bu.s;
      }
#pragma unroll
      for (int fm = 0; fm < 4; ++fm)
#pragma unroll
        for (int fn = 0; fn < 4; ++fn)
          acc[fm][fn] = __builtin_amdgcn_mfma_f32_16x16x32_bf16(af[fm], bfr[fn], acc[fm][fn], 0, 0, 0);
    }
  }

#pragma unroll
  for (int fm = 0; fm < 4; ++fm) {
#pragma unroll
    for (int fn = 0; fn < 4; ++fn) {
      int pg = p0 + p_base + fn * 16 + col;
#pragma unroll
      for (int r = 0; r < 4; ++r) {
        int oo = o_base + fm * 16 + q * 4 + r;
        size_t oi = ((size_t)(bb * 128 + oo) << 14) + pg;
        out[oi] = acc[fm][fn][r] + b4[oo] + x[oi];
      }
    }
  }
}

// ---------------------------------------------------------------------------
extern "C" void kernel_launch(void* const* d_in, const int* in_sizes, int n_in,
                              void* d_out, int out_size, void* d_ws, size_t ws_size,
                              hipStream_t stream) {
  const float* x  = (const float*)d_in[0];
  const float* w1 = (const float*)d_in[1];
  const float* b1 = (const float*)d_in[2];
  const float* w2 = (const float*)d_in[3];
  const float* b2 = (const float*)d_in[4];
  const float* w3 = (const float*)d_in[5];
  const float* b3 = (const float*)d_in[6];
  const float* w4 = (const float*)d_in[7];
  const float* b4 = (const float*)d_in[8];
  float* out = (float*)d_out;

  char* ws = (char*)d_ws;
  uint16_t* w4s  = (uint16_t*)ws;              // 163840 B
  float*    cw2  = (float*)(ws + 163840);      // 23040 B
  float*    cw3  = (float*)(ws + 186880);      // 23040 B
  float*    bsum = (float*)(ws + 209920);      // 2560 B
  uint32_t* y    = (uint32_t*)(ws + (1 << 20));

  const size_t per_b = (size_t)320 * 16384 * 4;  // 20 MiB per batch
  int nbc = 4;
  while (nbc > 1 && (size_t)(1 << 20) + (size_t)nbc * per_b > ws_size) nbc >>= 1;

  hipLaunchKernelGGL(prep_kernel, dim3(320), dim3(256), 0, stream,
                     w1, b1, w2, b2, w3, b3, w4, w4s, cw2, cw3, bsum);
  for (int b0 = 0; b0 < 8; b0 += nbc) {
    int nb = (8 - b0) < nbc ? (8 - b0) : nbc;
    hipLaunchKernelGGL(dw_kernel, dim3(4, 64, nb), dim3(256), 0, stream,
                       x, cw2, cw3, bsum, y, b0);
    hipLaunchKernelGGL(gemm_kernel, dim3(128, nb), dim3(256), 0, stream,
                       w4s, y, x, b4, out, b0);
  }
}